// Round 13
// baseline (310.815 us; speedup 1.0000x reference)
//
#include <hip/hip_runtime.h>

// Problem constants (B=4, V=1024, L=2048, H=2048, TEMP=1, EPS=1e-12)
#define H_ 2048

typedef __attribute__((ext_vector_type(8))) short short8;
typedef __attribute__((ext_vector_type(4))) float f32x4;
typedef __attribute__((ext_vector_type(16))) float f32x16;
typedef __attribute__((ext_vector_type(4))) unsigned int u32x4;
typedef __attribute__((ext_vector_type(4))) unsigned short u16x4;

__device__ __forceinline__ unsigned short f2bf(float f) {
  unsigned int u = __builtin_bit_cast(unsigned int, f);
  u += 0x7FFFu + ((u >> 16) & 1u);  // RTNE
  return (unsigned short)(u >> 16);
}
__device__ __forceinline__ float bf2f(unsigned short h) {
  unsigned int u = ((unsigned int)h) << 16;
  return __builtin_bit_cast(float, u);
}
__device__ __forceinline__ unsigned int pk2(float a, float b) {
  return (unsigned int)f2bf(a) | ((unsigned int)f2bf(b) << 16);
}

#define GLDS16(gp, lp)                                                 \
  __builtin_amdgcn_global_load_lds(                                    \
      (const __attribute__((address_space(1))) void*)(gp),             \
      (__attribute__((address_space(3))) void*)(lp), 16, 0, 0)

// ---------------------------------------------------------------------------
// prep: per-row 1/max(||row||,eps) + raw bf16 copy; rows >= validRows -> zeros
// ---------------------------------------------------------------------------
__global__ __launch_bounds__(256) void prep_rows(
    const float* __restrict__ in, long sIn,
    unsigned short* __restrict__ outBf, long sOut,
    float* __restrict__ rnorm, int validRows) {
  const int tid = threadIdx.x;
  const int r = blockIdx.x, b = blockIdx.y;
  unsigned short* orow = outBf + (long)b * sOut + (long)r * H_ + tid * 8;
  if (r >= validRows) {
    *(u32x4*)orow = (u32x4){0u, 0u, 0u, 0u};
    if (tid == 0) rnorm[b * H_ + r] = 0.f;
    return;
  }
  const float* row = in + (long)b * sIn + (long)r * H_ + tid * 8;
  f32x4 x0 = *(const f32x4*)row;
  f32x4 x1 = *(const f32x4*)(row + 4);
  float ss = x0[0]*x0[0] + x0[1]*x0[1] + x0[2]*x0[2] + x0[3]*x0[3]
           + x1[0]*x1[0] + x1[1]*x1[1] + x1[2]*x1[2] + x1[3]*x1[3];
#pragma unroll
  for (int o = 32; o; o >>= 1) ss += __shfl_xor(ss, o, 64);
  __shared__ float red[4];
  if ((tid & 63) == 0) red[tid >> 6] = ss;
  __syncthreads();
  if (tid == 0) {
    float tot = red[0] + red[1] + red[2] + red[3];
    rnorm[b * H_ + r] = 1.f / fmaxf(sqrtf(tot), 1e-12f);
  }
  u32x4 o;
  o[0] = pk2(x0[0], x0[1]); o[1] = pk2(x0[2], x0[3]);
  o[2] = pk2(x1[0], x1[1]); o[3] = pk2(x1[2], x1[3]);
  *(u32x4*)orow = o;
}

// ---------------------------------------------------------------------------
// column sums from bf16 copies; vis padded rows (y>=4) are zeros -> skipped
// ---------------------------------------------------------------------------
__global__ __launch_bounds__(256) void col_sum_part_bf(
    const unsigned short* __restrict__ visBf,
    const unsigned short* __restrict__ langBf, float* __restrict__ part) {
  const int h = blockIdx.x * 256 + threadIdx.x;
  const int y = blockIdx.y;
  const int which = blockIdx.z & 1;
  const int b = blockIdx.z >> 1;
  const long sP = 2048L * 2048;
  float s = 0.f;
  if (!(which == 0 && y >= 4)) {
    const unsigned short* p =
        (which ? langBf : visBf) + (long)b * sP + (long)(y * 256) * H_ + h;
#pragma unroll 4
    for (int i = 0; i < 256; ++i) s += bf2f(p[(long)i * H_]);
  }
  part[(((long)which * 4 + b) * 8 + y) * H_ + h] = s;
}

__global__ __launch_bounds__(256) void col_sum_final(
    const float* __restrict__ part, float* __restrict__ vavg,
    float* __restrict__ lavg) {
  const int h = blockIdx.x * 256 + threadIdx.x;
  const int b = blockIdx.y;
  const int which = blockIdx.z;
  const float* p = part + (((long)which * 4 + b) * 8) * H_ + h;
  float s = 0.f;
#pragma unroll
  for (int y = 0; y < 8; ++y) s += p[y * H_];
  (which ? lavg : vavg)[b * H_ + h] = s * (1.f / 2048.f);
}

// ---------------------------------------------------------------------------
// bias GEMV: bias[b,h] = sum_{d<2048} avg[b,d] * W[h*4096 + d]
// ---------------------------------------------------------------------------
__global__ __launch_bounds__(256) void bias_gemv(
    const float* __restrict__ W, const float* __restrict__ avg,
    float* __restrict__ bias) {
  const int lane = threadIdx.x & 63;
  const int wv = threadIdx.x >> 6;
  const int h = blockIdx.x * 4 + wv;
  const float* wrow = W + (long)h * 4096;
  float a0 = 0.f, a1 = 0.f, a2 = 0.f, a3 = 0.f;
#pragma unroll
  for (int i = 0; i < 8; ++i) {
    const int d = i * 256 + lane * 4;
    f32x4 w4 = *(const f32x4*)(wrow + d);
    f32x4 v0 = *(const f32x4*)(avg + 0 * H_ + d);
    f32x4 v1 = *(const f32x4*)(avg + 1 * H_ + d);
    f32x4 v2 = *(const f32x4*)(avg + 2 * H_ + d);
    f32x4 v3 = *(const f32x4*)(avg + 3 * H_ + d);
    a0 += w4[0]*v0[0] + w4[1]*v0[1] + w4[2]*v0[2] + w4[3]*v0[3];
    a1 += w4[0]*v1[0] + w4[1]*v1[1] + w4[2]*v1[2] + w4[3]*v1[3];
    a2 += w4[0]*v2[0] + w4[1]*v2[1] + w4[2]*v2[2] + w4[3]*v2[3];
    a3 += w4[0]*v3[0] + w4[1]*v3[1] + w4[2]*v3[2] + w4[3]*v3[3];
  }
#pragma unroll
  for (int o = 32; o; o >>= 1) {
    a0 += __shfl_xor(a0, o, 64);
    a1 += __shfl_xor(a1, o, 64);
    a2 += __shfl_xor(a2, o, 64);
    a3 += __shfl_xor(a3, o, 64);
  }
  if (lane == 0) {
    bias[0 * H_ + h] = a0; bias[1 * H_ + h] = a1;
    bias[2 * H_ + h] = a2; bias[3 * H_ + h] = a3;
  }
}

// ---------------------------------------------------------------------------
// transpose langBf (bf16 [b][l][h]) -> lang_T (bf16 [b][h][l])
// ---------------------------------------------------------------------------
__global__ __launch_bounds__(256) void transpose_bf(
    const unsigned short* __restrict__ in, unsigned short* __restrict__ out) {
  __shared__ unsigned short tle[64][72];
  const int b = blockIdx.z;
  const int l0 = blockIdx.y * 64, h0 = blockIdx.x * 64;
  const unsigned short* inb = in + (long)b * (2048L * 2048);
  unsigned short* outb = out + (long)b * (2048L * 2048);
#pragma unroll
  for (int i = 0; i < 16; ++i) {
    const int idx = i * 256 + threadIdx.x;
    const int r = idx >> 6, c = idx & 63;
    tle[r][c] = inb[(long)(l0 + r) * H_ + h0 + c];
  }
  __syncthreads();
#pragma unroll
  for (int i = 0; i < 16; ++i) {
    const int idx = i * 256 + threadIdx.x;
    const int r = idx >> 6, c = idx & 63;  // r = h-local, c = l-local
    outb[(long)(h0 + r) * H_ + l0 + c] = tle[c][r];
  }
}

// ---------------------------------------------------------------------------
// extract W[:, 2048:4096] as bf16 row-major [h][k]
// ---------------------------------------------------------------------------
__global__ __launch_bounds__(256) void extract_whi(
    const float* __restrict__ Wvl, const float* __restrict__ Wlv,
    unsigned short* __restrict__ WvlHi, unsigned short* __restrict__ WlvHi) {
  const int h = blockIdx.x;
  const int which = blockIdx.y;
  const float* src = (which ? Wlv : Wvl) + (long)h * 4096 + 2048 + threadIdx.x * 8;
  unsigned short* dst = (which ? WlvHi : WvlHi) + (long)h * H_ + threadIdx.x * 8;
  f32x4 x0 = *(const f32x4*)src;
  f32x4 x1 = *(const f32x4*)(src + 4);
  u32x4 o;
  o[0] = pk2(x0[0], x0[1]); o[1] = pk2(x0[2], x0[3]);
  o[2] = pk2(x1[0], x1[1]); o[3] = pk2(x1[2], x1[3]);
  *(u32x4*)dst = o;
}

// ---------------------------------------------------------------------------
// fused rows 1024..2047 = lavg (exact: softmax over zero scores is uniform)
// ---------------------------------------------------------------------------
__global__ __launch_bounds__(256) void bcast_fused(
    const float* __restrict__ lavg, float* __restrict__ fused) {
  const int b = blockIdx.y;
  const long r = 1024 + blockIdx.x;
  const int c = threadIdx.x * 8;
  f32x4 v0 = *(const f32x4*)(lavg + b * H_ + c);
  f32x4 v1 = *(const f32x4*)(lavg + b * H_ + c + 4);
  float* dst = fused + (long)b * (2048L * 2048) + r * H_ + c;
  *(f32x4*)dst = v0;
  *(f32x4*)(dst + 4) = v1;
}

// ---------------------------------------------------------------------------
// row softmax in place over bf16; grid = 4096 (b = x>>10, row = x&1023)
// ---------------------------------------------------------------------------
__global__ __launch_bounds__(256) void softmax_rows(unsigned short* __restrict__ S) {
  const int tid = threadIdx.x;
  const int lane = tid & 63, wv = tid >> 6;
  const int b = blockIdx.x >> 10;
  const int r = blockIdx.x & 1023;
  unsigned short* rowp =
      S + (long)b * (2048L * 2048) + (long)r * H_ + tid * 8;
  u32x4 raw = *(const u32x4*)rowp;
  float v[8];
#pragma unroll
  for (int i = 0; i < 4; ++i) {
    v[2 * i]     = bf2f((unsigned short)(raw[i] & 0xFFFFu));
    v[2 * i + 1] = bf2f((unsigned short)(raw[i] >> 16));
  }
  float mx = v[0];
#pragma unroll
  for (int i = 1; i < 8; ++i) mx = fmaxf(mx, v[i]);
#pragma unroll
  for (int o = 32; o; o >>= 1) mx = fmaxf(mx, __shfl_xor(mx, o, 64));
  __shared__ float red[4];
  if (lane == 0) red[wv] = mx;
  __syncthreads();
  const float MX = fmaxf(fmaxf(red[0], red[1]), fmaxf(red[2], red[3]));
  float p[8], s = 0.f;
#pragma unroll
  for (int i = 0; i < 8; ++i) { p[i] = __expf(v[i] - MX); s += p[i]; }
#pragma unroll
  for (int o = 32; o; o >>= 1) s += __shfl_xor(s, o, 64);
  __syncthreads();
  if (lane == 0) red[wv] = s;
  __syncthreads();
  const float inv = 1.f / (red[0] + red[1] + red[2] + red[3]);
  u32x4 o;
#pragma unroll
  for (int i = 0; i < 4; ++i) o[i] = pk2(p[2 * i] * inv, p[2 * i + 1] * inv);
  *(u32x4*)rowp = o;
}

// ---------------------------------------------------------------------------
// NT GEMM (C = A * B^T), 128x128 tile, BK=64, 4 waves (2M x 2N), 256 threads,
// 64KB double-buffered LDS -> 2 blocks/CU. R13: core switched to
// v_mfma_f32_32x32x16_bf16 (2x FLOP per MFMA -> half the MFMA instruction
// count and issue slots; LDS bytes unchanged). Per wave: 2x2 blocks of 32x32,
// 4 K-steps of 16 per BK=64 tile. Same counted vmcnt(8) ledger; same
// conflict-free XOR swizzle (chunk = 2*ks + (lane>>5), row = lane&31 -> 8
// lanes/bank-quad uniform); XCD block swizzle. ALL epilogues via rotated-LDS
// f32 tile -> vectorized coalesced I/O (MODE 0 scales rv*rl in vector pass).
// C/D 32x32 layout: col=lane&31, row=(r&3)+8*(r>>2)+4*(lane>>5) [m74/m101].
// ---------------------------------------------------------------------------
struct EpArgs {
  unsigned short* Sout; const float* rv; const float* rl;     // MODE 0
  float* Fout;                                                // MODE 1
  const unsigned short* residBf; const float* fusedIn;        // MODE 3 side 1
  const float* bias; float* Oout;
  long sResid, sFused, sOut;
  const unsigned short* A2; const unsigned short* B2;         // MODE 3 side 2
  const unsigned short* residBf2; const float* bias2; float* Oout2;
  long sResid2, sOut2;
  const float* lavg;                                          // MODE 3
};

#define BAR_ asm volatile("s_barrier" ::: "memory")
#define WAITV_(n) asm volatile("s_waitcnt vmcnt(" #n ")" ::: "memory")
#define LGKM0_ asm volatile("s_waitcnt lgkmcnt(0)" ::: "memory")
#define SB_ __builtin_amdgcn_sched_barrier(0)

template <int MODE>
__global__ __launch_bounds__(256, 2) void gemm_nt(
    const unsigned short* __restrict__ A, long sA,
    const unsigned short* __restrict__ B, long sB, EpArgs ep) {
  // LDS bytes: buffer P at P*32768; A [0,16384), B [16384,32768) within buf
  __shared__ unsigned short LDS[32768];  // 64 KB

  const int tid = threadIdx.x;
  const int lane = tid & 63;
  const int wave = tid >> 6;  // 0..3

  // XCD-aware bijective block swizzle (nwg % 8 == 0 for all our grids)
  const int gx = gridDim.x, gy = gridDim.y;
  const int nwg = gx * gy * gridDim.z;
  const int lin = blockIdx.x + gx * (blockIdx.y + gy * blockIdx.z);
  const int swz = (lin & 7) * (nwg >> 3) + (lin >> 3);
  const int bx = swz % gx;
  const int rest = swz / gx;
  const int by = rest % gy;
  const int b = rest / gy;
  const int bn = bx << 7;

  // per-mode A/B/row selection (block-uniform)
  int bm;
  bool second = false;
  const unsigned short* Ab;
  const unsigned short* Bb;
  const unsigned short* RbBf = nullptr;
  const float *Fb = nullptr, *biasb = nullptr;
  float* Ob = nullptr;
  if (MODE == 3) {
    second = (by >= 16);
    bm = (second ? by - 16 : by) << 7;
    Ab = (second ? ep.A2 : A) + (long)b * sA;
    Bb = second ? ep.B2 : B;
    RbBf = (second ? ep.residBf2 : ep.residBf) +
           (long)b * (second ? ep.sResid2 : ep.sResid);
    Ob = (second ? ep.Oout2 : ep.Oout) +
         (long)b * (second ? ep.sOut2 : ep.sOut);
    biasb = (second ? ep.bias2 : ep.bias) + b * H_;
    Fb = ep.fusedIn + (long)b * ep.sFused;
  } else {
    bm = by << 7;
    Ab = A + (long)b * sA;
    Bb = B + (long)b * sB;
  }

  // --- staging addressing (global_load_lds: linear dest, pre-swz source) ---
  const int srow = tid >> 3;                                 // 0..31
  const int colOff = (((tid & 7) ^ (srow & 7)) << 3);        // inv-swz k col
  const unsigned short* gA = Ab + (long)(bm + srow) * H_ + colOff;
  const unsigned short* gB = Bb + (long)(bn + srow) * H_ + colOff;
  const int ldst = wave * 512;  // elem base (HW adds lane*16B)

#define STAGE_(kt, P)                                               \
  do {                                                              \
    const unsigned short* a_ = gA + (kt) * 64;                      \
    const unsigned short* b_ = gB + (kt) * 64;                      \
    GLDS16(a_,           &LDS[(P) * 16384 + 0     + ldst]);         \
    GLDS16(a_ + 32 * H_, &LDS[(P) * 16384 + 2048  + ldst]);         \
    GLDS16(a_ + 64 * H_, &LDS[(P) * 16384 + 4096  + ldst]);         \
    GLDS16(a_ + 96 * H_, &LDS[(P) * 16384 + 6144  + ldst]);         \
    GLDS16(b_,           &LDS[(P) * 16384 + 8192  + ldst]);         \
    GLDS16(b_ + 32 * H_, &LDS[(P) * 16384 + 10240 + ldst]);         \
    GLDS16(b_ + 64 * H_, &LDS[(P) * 16384 + 12288 + ldst]);         \
    GLDS16(b_ + 96 * H_, &LDS[(P) * 16384 + 14336 + ldst]);         \
  } while (0)

  // --- fragment addressing (32x32x16: row = lane&31, k-half = lane>>5) ---
  const int row32 = lane & 31;
  const int khalf = lane >> 5;
  const int r7 = row32 & 7;
  const int wr = (wave >> 1) << 6;   // A row base: 0 or 64
  const int wc = (wave & 1) << 6;    // B col base: 0 or 64

  const unsigned ldsBase = (unsigned)(unsigned long long)(
      __attribute__((address_space(3))) const void*)LDS;
  const unsigned aRow = ldsBase + (unsigned)((wr + row32) * 128);
  const unsigned bRow = ldsBase + 16384u + (unsigned)((wc + row32) * 128);
  const unsigned kbA0 = aRow + (unsigned)(((0 + khalf) ^ r7) << 4);
  const unsigned kbA1 = aRow + (unsigned)(((2 + khalf) ^ r7) << 4);
  const unsigned kbA2 = aRow + (unsigned)(((4 + khalf) ^ r7) << 4);
  const unsigned kbA3 = aRow + (unsigned)(((6 + khalf) ^ r7) << 4);
  const unsigned kbB0 = bRow + (unsigned)(((0 + khalf) ^ r7) << 4);
  const unsigned kbB1 = bRow + (unsigned)(((2 + khalf) ^ r7) << 4);
  const unsigned kbB2 = bRow + (unsigned)(((4 + khalf) ^ r7) << 4);
  const unsigned kbB3 = bRow + (unsigned)(((6 + khalf) ^ r7) << 4);

#define DSRD_(dst, base, off) \
  asm volatile("ds_read_b128 %0, %1 offset:" #off : "=v"(dst) : "v"(base))

  f32x16 acc[2][2];
#pragma unroll
  for (int m = 0; m < 2; ++m)
#pragma unroll
    for (int n = 0; n < 2; ++n)
#pragma unroll
      for (int r = 0; r < 16; ++r) acc[m][n][r] = 0.f;
  short8 aF[2][4], bF[2][4];

  // m-block offset = 32 rows * 128B = 4096; buffer P adds 32768.
#define RDALL_P0                                               \
  do {                                                         \
    DSRD_(aF[0][0], kbA0, 0);    DSRD_(aF[1][0], kbA0, 4096);  \
    DSRD_(aF[0][1], kbA1, 0);    DSRD_(aF[1][1], kbA1, 4096);  \
    DSRD_(aF[0][2], kbA2, 0);    DSRD_(aF[1][2], kbA2, 4096);  \
    DSRD_(aF[0][3], kbA3, 0);    DSRD_(aF[1][3], kbA3, 4096);  \
    DSRD_(bF[0][0], kbB0, 0);    DSRD_(bF[1][0], kbB0, 4096);  \
    DSRD_(bF[0][1], kbB1, 0);    DSRD_(bF[1][1], kbB1, 4096);  \
    DSRD_(bF[0][2], kbB2, 0);    DSRD_(bF[1][2], kbB2, 4096);  \
    DSRD_(bF[0][3], kbB3, 0);    DSRD_(bF[1][3], kbB3, 4096);  \
  } while (0)
#define RDALL_P1                                                     \
  do {                                                               \
    DSRD_(aF[0][0], kbA0, 32768); DSRD_(aF[1][0], kbA0, 36864);      \
    DSRD_(aF[0][1], kbA1, 32768); DSRD_(aF[1][1], kbA1, 36864);      \
    DSRD_(aF[0][2], kbA2, 32768); DSRD_(aF[1][2], kbA2, 36864);      \
    DSRD_(aF[0][3], kbA3, 32768); DSRD_(aF[1][3], kbA3, 36864);      \
    DSRD_(bF[0][0], kbB0, 32768); DSRD_(bF[1][0], kbB0, 36864);      \
    DSRD_(bF[0][1], kbB1, 32768); DSRD_(bF[1][1], kbB1, 36864);      \
    DSRD_(bF[0][2], kbB2, 32768); DSRD_(bF[1][2], kbB2, 36864);      \
    DSRD_(bF[0][3], kbB3, 32768); DSRD_(bF[1][3], kbB3, 36864);      \
  } while (0)

#define MFMA16_                                                             \
  do {                                                                      \
    __builtin_amdgcn_s_setprio(1);                                          \
    _Pragma("unroll") for (int ks_ = 0; ks_ < 4; ++ks_)                     \
    _Pragma("unroll") for (int m_ = 0; m_ < 2; ++m_)                        \
    _Pragma("unroll") for (int n_ = 0; n_ < 2; ++n_)                        \
        acc[m_][n_] = __builtin_amdgcn_mfma_f32_32x32x16_bf16(              \
            aF[m_][ks_], bF[n_][ks_], acc[m_][n_], 0, 0, 0);                \
    __builtin_amdgcn_s_setprio(0);                                          \
  } while (0)

  // prologue: stage tiles 0 (buf0), 1 (buf1); wait tile0 landed; publish
  STAGE_(0, 0); STAGE_(1, 1);
  WAITV_(8);
  BAR_;

  // steady state: 32 K-tiles (BK=64); t = 0..29 stage t+2
  for (int tt = 0; tt < 15; ++tt) {
    const int t2 = tt * 2;
    RDALL_P0; LGKM0_; SB_;
    BAR_;                       // all waves done reading buf0 (WAR)
    STAGE_(t2 + 2, 0);          // restage buf0 with tile t2+2
    WAITV_(8);                  // tile t2+1 landed
    BAR_;                       // publish t2+1
    MFMA16_;
    RDALL_P1; LGKM0_; SB_;
    BAR_;
    STAGE_(t2 + 3, 1);
    WAITV_(8);
    BAR_;
    MFMA16_;
  }
  // t = 30 (buf0): no stage; drain to publish tile 31
  RDALL_P0; LGKM0_; SB_;
  BAR_;
  WAITV_(0);
  BAR_;
  MFMA16_;
  // t = 31 (buf1)
  RDALL_P1; LGKM0_; SB_;
  MFMA16_;

  // Epilogue: scatter acc into rotated f32 [128][128] LDS tile, then
  // vectorized coalesced global I/O. 32x32 C/D layout:
  // col = lane&31, row = (r&3) + 8*(r>>2) + 4*khalf  [m74/m101].
  float* LF = (float*)LDS;
  __syncthreads();  // all waves' final LDS reads complete before overwrite
#pragma unroll
  for (int m = 0; m < 2; ++m)
#pragma unroll
    for (int n = 0; n < 2; ++n)
#pragma unroll
      for (int r = 0; r < 16; ++r) {
        const int row = wr + m * 32 + (r & 3) + 8 * (r >> 2) + 4 * khalf;
        const int col = wc + n * 32 + row32;
        LF[row * 128 + ((col + 4 * row) & 127)] = acc[m][n][r];
      }
  __syncthreads();
  const int r8 = tid >> 5;          // 0..7
  const int c4 = (tid & 31) * 4;    // 0..124

  if (MODE == 0) {
    unsigned short* Sb = ep.Sout + (long)b * (H_ * (long)H_);
    const f32x4 rl4 = *(const f32x4*)&ep.rl[b * H_ + bn + c4];
#pragma unroll
    for (int it = 0; it < 16; ++it) {
      const int r = it * 8 + r8;
      const float rvr = ep.rv[b * H_ + bm + r];
      f32x4 v = *(const f32x4*)&LF[r * 128 + ((c4 + 4 * r) & 127)];
      u16x4 o;
#pragma unroll
      for (int k = 0; k < 4; ++k) o[k] = f2bf(v[k] * rvr * rl4[k]);
      *(u16x4*)&Sb[(long)(bm + r) * H_ + bn + c4] = o;
    }
  } else if (MODE == 1) {
    float* Fo = ep.Fout + (long)b * (H_ * (long)H_);
#pragma unroll
    for (int it = 0; it < 16; ++it) {
      const int r = it * 8 + r8;
      f32x4 v = *(const f32x4*)&LF[r * 128 + ((c4 + 4 * r) & 127)];
      *(f32x4*)&Fo[(long)(bm + r) * H_ + bn + c4] = v;
    }
  } else {
    const f32x4 bvv = *(const f32x4*)&biasb[bn + c4];
    // language-gate blocks fully in rows>=1024: fused row == lavg (exact)
    const bool useLavg = (!second) && (bm >= 1024);
    f32x4 lavgv = (f32x4){0.f, 0.f, 0.f, 0.f};
    if (useLavg) lavgv = *(const f32x4*)&ep.lavg[b * H_ + bn + c4];
#pragma unroll
    for (int it = 0; it < 16; ++it) {
      const int r = it * 8 + r8;
      f32x4 v = *(const f32x4*)&LF[r * 128 + ((c4 + 4 * r) & 127)];
      const long off = (long)(bm + r) * H_ + bn + c4;
      const f32x4 fv = useLavg ? lavgv : *(const f32x4*)&Fb[off];
      const u16x4 rb4 = *(const u16x4*)&RbBf[off];
      f32x4 o;
#pragma unroll
      for (int k = 0; k < 4; ++k) {
        const float x = v[k] + bvv[k];
        const float g = 1.f / (1.f + __expf(-x));
        o[k] = bf2f(rb4[k]) + fv[k] * g;
      }
      *(f32x4*)&Ob[off] = o;
    }
  }
#undef STAGE_
#undef DSRD_
#undef RDALL_P0
#undef RDALL_P1
#undef MFMA16_
}

// ---------------------------------------------------------------------------
extern "C" void kernel_launch(void* const* d_in, const int* in_sizes, int n_in,
                              void* d_out, int out_size, void* d_ws,
                              size_t ws_size, hipStream_t stream) {
  (void)in_sizes; (void)n_in; (void)out_size; (void)ws_size;
  const float* vis = (const float*)d_in[0];   // [4,1024,2048]
  const float* lang = (const float*)d_in[1];  // [4,2048,2048]
  const float* Wvl = (const float*)d_in[2];   // [2048,4096]
  const float* Wlv = (const float*)d_in[3];   // [2048,4096]

  // d_out regions: fused | vision_output | language_output
  float* out = (float*)d_out;
  float* fused = out;                      // 16,777,216 f32
  float* vis_out = out + 16777216;         //  8,388,608 f32
  float* lang_out = out + 25165824;        // 16,777,216 f32
  // scratch reuse of not-yet-final output regions:
  unsigned short* S = (unsigned short*)lang_out;     // scores/P bf16
  unsigned short* langT = (unsigned short*)vis_out;  // lang^T bf16

  // workspace layout
  char* w = (char*)d_ws;
  unsigned short* vis_bf = (unsigned short*)w;               // [4,2048,2048] bf16 (rows<1024 valid)
  unsigned short* lang_bf = (unsigned short*)(w + 33554432); // [4,2048,2048] bf16
  unsigned short* WvlHi = (unsigned short*)(w + 67108864);   // [2048,2048] bf16
  unsigned short* WlvHi = (unsigned short*)(w + 75497472);   // [2048,2048] bf16
  float* rv      = (float*)(w + 83886080);
  float* rl      = (float*)(w + 83918848);
  float* vavg    = (float*)(w + 83951616);
  float* lavg    = (float*)(w + 83984384);
  float* bias_vl = (float*)(w + 84017152);
  float* bias_lv = (float*)(w + 84049920);
  float* part    = (float*)(w + 84082688);  // 512KB partial col sums

  const long sV = 1024L * 2048, sL = 2048L * 2048, sP = 2048L * 2048;

  // vis: only the 1024 valid rows are ever read (GEMM1 y<8, gate by<24 vis
  // side bm<1024, col_sum y<4) -> skip writing padded rows entirely.
  prep_rows<<<dim3(1024, 4), 256, 0, stream>>>(vis, sV, vis_bf, sP, rv, 1024);
  prep_rows<<<dim3(2048, 4), 256, 0, stream>>>(lang, sL, lang_bf, sP, rl, 2048);
  col_sum_part_bf<<<dim3(8, 8, 8), 256, 0, stream>>>(vis_bf, lang_bf, part);
  col_sum_final<<<dim3(8, 4, 2), 256, 0, stream>>>(part, vavg, lavg);
  bias_gemv<<<512, 256, 0, stream>>>(Wvl, vavg, bias_vl);
  bias_gemv<<<512, 256, 0, stream>>>(Wlv, lavg, bias_lv);
  transpose_bf<<<dim3(32, 32, 4), 256, 0, stream>>>(lang_bf, langT);
  extract_whi<<<dim3(2048, 2), 256, 0, stream>>>(Wvl, Wlv, WvlHi, WlvHi);
  // fused rows >= 1024 are exactly lavg (uniform softmax over zero scores)
  bcast_fused<<<dim3(1024, 4), 256, 0, stream>>>(lavg, fused);

  // GEMM1: scores S[b,v<1024,l] = (vis . lang) * rv * rl  -> bf16
  EpArgs e1 = {};
  e1.Sout = S; e1.rv = rv; e1.rl = rl;
  gemm_nt<0><<<dim3(16, 8, 4), 256, 0, stream>>>(vis_bf, sP, lang_bf, sP, e1);

  softmax_rows<<<4096, 256, 0, stream>>>(S);

  // GEMM2: fused[b,v<1024,h] = P . lang  (B = lang^T, NT form) -> f32
  EpArgs e2 = {};
  e2.Fout = fused;
  gemm_nt<1><<<dim3(16, 8, 4), 256, 0, stream>>>(S, sP, langT, sP, e2);

  // GEMM3+4 merged: by<16 -> language_output, by>=16 -> vision_output
  EpArgs e34 = {};
  e34.residBf = lang_bf; e34.sResid = sP;
  e34.fusedIn = fused; e34.sFused = sP;
  e34.bias = bias_vl; e34.Oout = lang_out; e34.sOut = sL;
  e34.A2 = vis_bf; e34.B2 = WlvHi;
  e34.residBf2 = vis_bf; e34.sResid2 = sP;
  e34.bias2 = bias_lv; e34.Oout2 = vis_out; e34.sOut2 = sV;
  e34.lavg = lavg;
  gemm_nt<3><<<dim3(16, 24, 4), 256, 0, stream>>>(lang_bf, sP, WvlHi, 0L, e34);
}

// Round 14
// 290.146 us; speedup vs baseline: 1.0712x; 1.0712x over previous
//
#include <hip/hip_runtime.h>

// Problem constants (B=4, V=1024, L=2048, H=2048, TEMP=1, EPS=1e-12)
#define H_ 2048

typedef __attribute__((ext_vector_type(8))) short short8;
typedef __attribute__((ext_vector_type(4))) float f32x4;
typedef __attribute__((ext_vector_type(4))) unsigned int u32x4;
typedef __attribute__((ext_vector_type(4))) unsigned short u16x4;

__device__ __forceinline__ unsigned short f2bf(float f) {
  unsigned int u = __builtin_bit_cast(unsigned int, f);
  u += 0x7FFFu + ((u >> 16) & 1u);  // RTNE
  return (unsigned short)(u >> 16);
}
__device__ __forceinline__ float bf2f(unsigned short h) {
  unsigned int u = ((unsigned int)h) << 16;
  return __builtin_bit_cast(float, u);
}
__device__ __forceinline__ unsigned int pk2(float a, float b) {
  return (unsigned int)f2bf(a) | ((unsigned int)f2bf(b) << 16);
}

#define GLDS16(gp, lp)                                                 \
  __builtin_amdgcn_global_load_lds(                                    \
      (const __attribute__((address_space(1))) void*)(gp),             \
      (__attribute__((address_space(3))) void*)(lp), 16, 0, 0)

// ---------------------------------------------------------------------------
// prep: per-row 1/max(||row||,eps) + raw bf16 copy; rows >= validRows -> zeros
// ---------------------------------------------------------------------------
__global__ __launch_bounds__(256) void prep_rows(
    const float* __restrict__ in, long sIn,
    unsigned short* __restrict__ outBf, long sOut,
    float* __restrict__ rnorm, int validRows) {
  const int tid = threadIdx.x;
  const int r = blockIdx.x, b = blockIdx.y;
  unsigned short* orow = outBf + (long)b * sOut + (long)r * H_ + tid * 8;
  if (r >= validRows) {
    *(u32x4*)orow = (u32x4){0u, 0u, 0u, 0u};
    if (tid == 0) rnorm[b * H_ + r] = 0.f;
    return;
  }
  const float* row = in + (long)b * sIn + (long)r * H_ + tid * 8;
  f32x4 x0 = *(const f32x4*)row;
  f32x4 x1 = *(const f32x4*)(row + 4);
  float ss = x0[0]*x0[0] + x0[1]*x0[1] + x0[2]*x0[2] + x0[3]*x0[3]
           + x1[0]*x1[0] + x1[1]*x1[1] + x1[2]*x1[2] + x1[3]*x1[3];
#pragma unroll
  for (int o = 32; o; o >>= 1) ss += __shfl_xor(ss, o, 64);
  __shared__ float red[4];
  if ((tid & 63) == 0) red[tid >> 6] = ss;
  __syncthreads();
  if (tid == 0) {
    float tot = red[0] + red[1] + red[2] + red[3];
    rnorm[b * H_ + r] = 1.f / fmaxf(sqrtf(tot), 1e-12f);
  }
  u32x4 o;
  o[0] = pk2(x0[0], x0[1]); o[1] = pk2(x0[2], x0[3]);
  o[2] = pk2(x1[0], x1[1]); o[3] = pk2(x1[2], x1[3]);
  *(u32x4*)orow = o;
}

// ---------------------------------------------------------------------------
// column sums from bf16 copies; vis padded rows (y>=4) are zeros -> skipped
// ---------------------------------------------------------------------------
__global__ __launch_bounds__(256) void col_sum_part_bf(
    const unsigned short* __restrict__ visBf,
    const unsigned short* __restrict__ langBf, float* __restrict__ part) {
  const int h = blockIdx.x * 256 + threadIdx.x;
  const int y = blockIdx.y;
  const int which = blockIdx.z & 1;
  const int b = blockIdx.z >> 1;
  const long sP = 2048L * 2048;
  float s = 0.f;
  if (!(which == 0 && y >= 4)) {
    const unsigned short* p =
        (which ? langBf : visBf) + (long)b * sP + (long)(y * 256) * H_ + h;
#pragma unroll 4
    for (int i = 0; i < 256; ++i) s += bf2f(p[(long)i * H_]);
  }
  part[(((long)which * 4 + b) * 8 + y) * H_ + h] = s;
}

__global__ __launch_bounds__(256) void col_sum_final(
    const float* __restrict__ part, float* __restrict__ vavg,
    float* __restrict__ lavg) {
  const int h = blockIdx.x * 256 + threadIdx.x;
  const int b = blockIdx.y;
  const int which = blockIdx.z;
  const float* p = part + (((long)which * 4 + b) * 8) * H_ + h;
  float s = 0.f;
#pragma unroll
  for (int y = 0; y < 8; ++y) s += p[y * H_];
  (which ? lavg : vavg)[b * H_ + h] = s * (1.f / 2048.f);
}

// ---------------------------------------------------------------------------
// bias GEMV: bias[b,h] = sum_{d<2048} avg[b,d] * W[h*4096 + d]
// ---------------------------------------------------------------------------
__global__ __launch_bounds__(256) void bias_gemv(
    const float* __restrict__ W, const float* __restrict__ avg,
    float* __restrict__ bias) {
  const int lane = threadIdx.x & 63;
  const int wv = threadIdx.x >> 6;
  const int h = blockIdx.x * 4 + wv;
  const float* wrow = W + (long)h * 4096;
  float a0 = 0.f, a1 = 0.f, a2 = 0.f, a3 = 0.f;
#pragma unroll
  for (int i = 0; i < 8; ++i) {
    const int d = i * 256 + lane * 4;
    f32x4 w4 = *(const f32x4*)(wrow + d);
    f32x4 v0 = *(const f32x4*)(avg + 0 * H_ + d);
    f32x4 v1 = *(const f32x4*)(avg + 1 * H_ + d);
    f32x4 v2 = *(const f32x4*)(avg + 2 * H_ + d);
    f32x4 v3 = *(const f32x4*)(avg + 3 * H_ + d);
    a0 += w4[0]*v0[0] + w4[1]*v0[1] + w4[2]*v0[2] + w4[3]*v0[3];
    a1 += w4[0]*v1[0] + w4[1]*v1[1] + w4[2]*v1[2] + w4[3]*v1[3];
    a2 += w4[0]*v2[0] + w4[1]*v2[1] + w4[2]*v2[2] + w4[3]*v2[3];
    a3 += w4[0]*v3[0] + w4[1]*v3[1] + w4[2]*v3[2] + w4[3]*v3[3];
  }
#pragma unroll
  for (int o = 32; o; o >>= 1) {
    a0 += __shfl_xor(a0, o, 64);
    a1 += __shfl_xor(a1, o, 64);
    a2 += __shfl_xor(a2, o, 64);
    a3 += __shfl_xor(a3, o, 64);
  }
  if (lane == 0) {
    bias[0 * H_ + h] = a0; bias[1 * H_ + h] = a1;
    bias[2 * H_ + h] = a2; bias[3 * H_ + h] = a3;
  }
}

// ---------------------------------------------------------------------------
// transpose langBf (bf16 [b][l][h]) -> lang_T (bf16 [b][h][l])
// ---------------------------------------------------------------------------
__global__ __launch_bounds__(256) void transpose_bf(
    const unsigned short* __restrict__ in, unsigned short* __restrict__ out) {
  __shared__ unsigned short tle[64][72];
  const int b = blockIdx.z;
  const int l0 = blockIdx.y * 64, h0 = blockIdx.x * 64;
  const unsigned short* inb = in + (long)b * (2048L * 2048);
  unsigned short* outb = out + (long)b * (2048L * 2048);
#pragma unroll
  for (int i = 0; i < 16; ++i) {
    const int idx = i * 256 + threadIdx.x;
    const int r = idx >> 6, c = idx & 63;
    tle[r][c] = inb[(long)(l0 + r) * H_ + h0 + c];
  }
  __syncthreads();
#pragma unroll
  for (int i = 0; i < 16; ++i) {
    const int idx = i * 256 + threadIdx.x;
    const int r = idx >> 6, c = idx & 63;  // r = h-local, c = l-local
    outb[(long)(h0 + r) * H_ + l0 + c] = tle[c][r];
  }
}

// ---------------------------------------------------------------------------
// extract W[:, 2048:4096] as bf16 row-major [h][k]
// ---------------------------------------------------------------------------
__global__ __launch_bounds__(256) void extract_whi(
    const float* __restrict__ Wvl, const float* __restrict__ Wlv,
    unsigned short* __restrict__ WvlHi, unsigned short* __restrict__ WlvHi) {
  const int h = blockIdx.x;
  const int which = blockIdx.y;
  const float* src = (which ? Wlv : Wvl) + (long)h * 4096 + 2048 + threadIdx.x * 8;
  unsigned short* dst = (which ? WlvHi : WvlHi) + (long)h * H_ + threadIdx.x * 8;
  f32x4 x0 = *(const f32x4*)src;
  f32x4 x1 = *(const f32x4*)(src + 4);
  u32x4 o;
  o[0] = pk2(x0[0], x0[1]); o[1] = pk2(x0[2], x0[3]);
  o[2] = pk2(x1[0], x1[1]); o[3] = pk2(x1[2], x1[3]);
  *(u32x4*)dst = o;
}

// ---------------------------------------------------------------------------
// fused rows 1024..2047 = lavg (exact: softmax over zero scores is uniform)
// ---------------------------------------------------------------------------
__global__ __launch_bounds__(256) void bcast_fused(
    const float* __restrict__ lavg, float* __restrict__ fused) {
  const int b = blockIdx.y;
  const long r = 1024 + blockIdx.x;
  const int c = threadIdx.x * 8;
  f32x4 v0 = *(const f32x4*)(lavg + b * H_ + c);
  f32x4 v1 = *(const f32x4*)(lavg + b * H_ + c + 4);
  float* dst = fused + (long)b * (2048L * 2048) + r * H_ + c;
  *(f32x4*)dst = v0;
  *(f32x4*)(dst + 4) = v1;
}

// ---------------------------------------------------------------------------
// row softmax in place over bf16; grid = 4096 (b = x>>10, row = x&1023)
// ---------------------------------------------------------------------------
__global__ __launch_bounds__(256) void softmax_rows(unsigned short* __restrict__ S) {
  const int tid = threadIdx.x;
  const int lane = tid & 63, wv = tid >> 6;
  const int b = blockIdx.x >> 10;
  const int r = blockIdx.x & 1023;
  unsigned short* rowp =
      S + (long)b * (2048L * 2048) + (long)r * H_ + tid * 8;
  u32x4 raw = *(const u32x4*)rowp;
  float v[8];
#pragma unroll
  for (int i = 0; i < 4; ++i) {
    v[2 * i]     = bf2f((unsigned short)(raw[i] & 0xFFFFu));
    v[2 * i + 1] = bf2f((unsigned short)(raw[i] >> 16));
  }
  float mx = v[0];
#pragma unroll
  for (int i = 1; i < 8; ++i) mx = fmaxf(mx, v[i]);
#pragma unroll
  for (int o = 32; o; o >>= 1) mx = fmaxf(mx, __shfl_xor(mx, o, 64));
  __shared__ float red[4];
  if (lane == 0) red[wv] = mx;
  __syncthreads();
  const float MX = fmaxf(fmaxf(red[0], red[1]), fmaxf(red[2], red[3]));
  float p[8], s = 0.f;
#pragma unroll
  for (int i = 0; i < 8; ++i) { p[i] = __expf(v[i] - MX); s += p[i]; }
#pragma unroll
  for (int o = 32; o; o >>= 1) s += __shfl_xor(s, o, 64);
  __syncthreads();
  if (lane == 0) red[wv] = s;
  __syncthreads();
  const float inv = 1.f / (red[0] + red[1] + red[2] + red[3]);
  u32x4 o;
#pragma unroll
  for (int i = 0; i < 4; ++i) o[i] = pk2(p[2 * i] * inv, p[2 * i + 1] * inv);
  *(u32x4*)rowp = o;
}

// ---------------------------------------------------------------------------
// NT GEMM (C = A * B^T), 128x128 tile, BK=64, 4 waves (2M x 2N), 256 threads,
// 64KB double-buffered LDS -> 2 blocks/CU. R14 = R12 core (16x16x32 MFMA,
// verified 0-bank-conflict swizzle; R13's 32x32 had intrinsic 4-way conflicts
// at 128B row stride, reverted) + rotated-LDS vector epilogue for ALL modes
// (MODE 0 scores now vectorized too: rv*rl scaling + coalesced u16x4 stores).
// Counted vmcnt(8) ledger; XCD block swizzle; MODE 3 bf16 residuals + lavg
// reuse for language rows >= 1024.
// ---------------------------------------------------------------------------
struct EpArgs {
  unsigned short* Sout; const float* rv; const float* rl;     // MODE 0
  float* Fout;                                                // MODE 1
  const unsigned short* residBf; const float* fusedIn;        // MODE 3 side 1
  const float* bias; float* Oout;
  long sResid, sFused, sOut;
  const unsigned short* A2; const unsigned short* B2;         // MODE 3 side 2
  const unsigned short* residBf2; const float* bias2; float* Oout2;
  long sResid2, sOut2;
  const float* lavg;                                          // MODE 3
};

#define BAR_ asm volatile("s_barrier" ::: "memory")
#define WAITV_(n) asm volatile("s_waitcnt vmcnt(" #n ")" ::: "memory")
#define LGKM0_ asm volatile("s_waitcnt lgkmcnt(0)" ::: "memory")
#define SB_ __builtin_amdgcn_sched_barrier(0)

template <int MODE>
__global__ __launch_bounds__(256, 2) void gemm_nt(
    const unsigned short* __restrict__ A, long sA,
    const unsigned short* __restrict__ B, long sB, EpArgs ep) {
  // LDS bytes: buffer P at P*32768; A [0,16384), B [16384,32768) within buf
  __shared__ unsigned short LDS[32768];  // 64 KB

  const int tid = threadIdx.x;
  const int lane = tid & 63;
  const int wave = tid >> 6;  // 0..3

  // XCD-aware bijective block swizzle (nwg % 8 == 0 for all our grids)
  const int gx = gridDim.x, gy = gridDim.y;
  const int nwg = gx * gy * gridDim.z;
  const int lin = blockIdx.x + gx * (blockIdx.y + gy * blockIdx.z);
  const int swz = (lin & 7) * (nwg >> 3) + (lin >> 3);
  const int bx = swz % gx;
  const int rest = swz / gx;
  const int by = rest % gy;
  const int b = rest / gy;
  const int bn = bx << 7;

  // per-mode A/B/row selection (block-uniform)
  int bm;
  bool second = false;
  const unsigned short* Ab;
  const unsigned short* Bb;
  const unsigned short* RbBf = nullptr;
  const float *Fb = nullptr, *biasb = nullptr;
  float* Ob = nullptr;
  if (MODE == 3) {
    second = (by >= 16);
    bm = (second ? by - 16 : by) << 7;
    Ab = (second ? ep.A2 : A) + (long)b * sA;
    Bb = second ? ep.B2 : B;
    RbBf = (second ? ep.residBf2 : ep.residBf) +
           (long)b * (second ? ep.sResid2 : ep.sResid);
    Ob = (second ? ep.Oout2 : ep.Oout) +
         (long)b * (second ? ep.sOut2 : ep.sOut);
    biasb = (second ? ep.bias2 : ep.bias) + b * H_;
    Fb = ep.fusedIn + (long)b * ep.sFused;
  } else {
    bm = by << 7;
    Ab = A + (long)b * sA;
    Bb = B + (long)b * sB;
  }

  // --- staging addressing (global_load_lds: linear dest, pre-swz source) ---
  const int srow = tid >> 3;                                 // 0..31
  const int colOff = (((tid & 7) ^ (srow & 7)) << 3);        // inv-swz k col
  const unsigned short* gA = Ab + (long)(bm + srow) * H_ + colOff;
  const unsigned short* gB = Bb + (long)(bn + srow) * H_ + colOff;
  const int ldst = wave * 512;  // elem base (HW adds lane*16B)

#define STAGE_(kt, P)                                               \
  do {                                                              \
    const unsigned short* a_ = gA + (kt) * 64;                      \
    const unsigned short* b_ = gB + (kt) * 64;                      \
    GLDS16(a_,           &LDS[(P) * 16384 + 0     + ldst]);         \
    GLDS16(a_ + 32 * H_, &LDS[(P) * 16384 + 2048  + ldst]);         \
    GLDS16(a_ + 64 * H_, &LDS[(P) * 16384 + 4096  + ldst]);         \
    GLDS16(a_ + 96 * H_, &LDS[(P) * 16384 + 6144  + ldst]);         \
    GLDS16(b_,           &LDS[(P) * 16384 + 8192  + ldst]);         \
    GLDS16(b_ + 32 * H_, &LDS[(P) * 16384 + 10240 + ldst]);         \
    GLDS16(b_ + 64 * H_, &LDS[(P) * 16384 + 12288 + ldst]);         \
    GLDS16(b_ + 96 * H_, &LDS[(P) * 16384 + 14336 + ldst]);         \
  } while (0)

  // --- fragment addressing (swizzled read; 16x16 layout, 0 conflicts) ---
  const int row16 = lane & 15;
  const int kg = lane >> 4;
  const int wr = (wave >> 1) << 6;   // 0 or 64
  const int wc = (wave & 1) << 6;    // 0 or 64
  const int x0 = ((kg ^ (row16 & 7)) << 4);        // ks=0 16B-group byte
  const int x1 = (((4 + kg) ^ (row16 & 7)) << 4);  // ks=1

  const unsigned bAk0 = (unsigned)(unsigned long long)(
      __attribute__((address_space(3))) const void*)LDS +
      (unsigned)((wr + row16) * 128 + x0);
  const unsigned bAk1 = bAk0 + (unsigned)(x1 - x0);
  const unsigned bBk0 = (unsigned)(unsigned long long)(
      __attribute__((address_space(3))) const void*)LDS +
      (unsigned)(16384 + (wc + row16) * 128 + x0);
  const unsigned bBk1 = bBk0 + (unsigned)(x1 - x0);

#define DSRD_(dst, base, off) \
  asm volatile("ds_read_b128 %0, %1 offset:" #off : "=v"(dst) : "v"(base))

  f32x4 acc[4][4];
#pragma unroll
  for (int m = 0; m < 4; ++m)
#pragma unroll
    for (int n = 0; n < 4; ++n) acc[m][n] = (f32x4){0.f, 0.f, 0.f, 0.f};
  short8 aF[4][2], bF[4][2];

  // m/n row stride = 16 rows * 128B = 2048 bytes; buffer P adds 32768.
#define RDALL_P0                                           \
  do {                                                     \
    DSRD_(aF[0][0], bAk0, 0);    DSRD_(aF[1][0], bAk0, 2048);  \
    DSRD_(aF[2][0], bAk0, 4096); DSRD_(aF[3][0], bAk0, 6144);  \
    DSRD_(aF[0][1], bAk1, 0);    DSRD_(aF[1][1], bAk1, 2048);  \
    DSRD_(aF[2][1], bAk1, 4096); DSRD_(aF[3][1], bAk1, 6144);  \
    DSRD_(bF[0][0], bBk0, 0);    DSRD_(bF[1][0], bBk0, 2048);  \
    DSRD_(bF[2][0], bBk0, 4096); DSRD_(bF[3][0], bBk0, 6144);  \
    DSRD_(bF[0][1], bBk1, 0);    DSRD_(bF[1][1], bBk1, 2048);  \
    DSRD_(bF[2][1], bBk1, 4096); DSRD_(bF[3][1], bBk1, 6144);  \
  } while (0)
#define RDALL_P1                                                   \
  do {                                                             \
    DSRD_(aF[0][0], bAk0, 32768); DSRD_(aF[1][0], bAk0, 34816);   \
    DSRD_(aF[2][0], bAk0, 36864); DSRD_(aF[3][0], bAk0, 38912);   \
    DSRD_(aF[0][1], bAk1, 32768); DSRD_(aF[1][1], bAk1, 34816);   \
    DSRD_(aF[2][1], bAk1, 36864); DSRD_(aF[3][1], bAk1, 38912);   \
    DSRD_(bF[0][0], bBk0, 32768); DSRD_(bF[1][0], bBk0, 34816);   \
    DSRD_(bF[2][0], bBk0, 36864); DSRD_(bF[3][0], bBk0, 38912);   \
    DSRD_(bF[0][1], bBk1, 32768); DSRD_(bF[1][1], bBk1, 34816);   \
    DSRD_(bF[2][1], bBk1, 36864); DSRD_(bF[3][1], bBk1, 38912);   \
  } while (0)

#define MFMA32_                                                             \
  do {                                                                      \
    __builtin_amdgcn_s_setprio(1);                                          \
    _Pragma("unroll") for (int ks_ = 0; ks_ < 2; ++ks_)                     \
    _Pragma("unroll") for (int m_ = 0; m_ < 4; ++m_)                        \
    _Pragma("unroll") for (int n_ = 0; n_ < 4; ++n_)                        \
        acc[m_][n_] = __builtin_amdgcn_mfma_f32_16x16x32_bf16(              \
            aF[m_][ks_], bF[n_][ks_], acc[m_][n_], 0, 0, 0);                \
    __builtin_amdgcn_s_setprio(0);                                          \
  } while (0)

  // prologue: stage tiles 0 (buf0), 1 (buf1); wait tile0 landed; publish
  STAGE_(0, 0); STAGE_(1, 1);
  WAITV_(8);
  BAR_;

  // steady state: 32 K-tiles (BK=64); t = 0..29 stage t+2
  for (int tt = 0; tt < 15; ++tt) {
    const int t2 = tt * 2;
    RDALL_P0; LGKM0_; SB_;
    BAR_;                       // all waves done reading buf0 (WAR)
    STAGE_(t2 + 2, 0);          // restage buf0 with tile t2+2
    WAITV_(8);                  // tile t2+1 landed
    BAR_;                       // publish t2+1
    MFMA32_;
    RDALL_P1; LGKM0_; SB_;
    BAR_;
    STAGE_(t2 + 3, 1);
    WAITV_(8);
    BAR_;
    MFMA32_;
  }
  // t = 30 (buf0): no stage; drain to publish tile 31
  RDALL_P0; LGKM0_; SB_;
  BAR_;
  WAITV_(0);
  BAR_;
  MFMA32_;
  // t = 31 (buf1)
  RDALL_P1; LGKM0_; SB_;
  MFMA32_;

  // Epilogue (ALL modes): scatter acc into rotated f32 [128][128] LDS tile
  // (col' = (col+4*row)&127: write banks consecutive, row-read 2-way = free),
  // then vectorized coalesced global I/O.
  // 16x16 C/D layout: col = lane&15, row = (lane>>4)*4 + j  [m89/m91].
  float* LF = (float*)LDS;
  __syncthreads();  // all waves' final LDS reads complete before overwrite
  const int lwr = wr + kg * 4;   // local row base of this lane's acc
  const int lwc = wc + row16;    // local col base
#pragma unroll
  for (int m = 0; m < 4; ++m)
#pragma unroll
    for (int n = 0; n < 4; ++n)
#pragma unroll
      for (int j = 0; j < 4; ++j) {
        const int r = lwr + m * 16 + j;
        const int c = lwc + n * 16;
        LF[r * 128 + ((c + 4 * r) & 127)] = acc[m][n][j];
      }
  __syncthreads();
  const int r8 = tid >> 5;          // 0..7
  const int c4 = (tid & 31) * 4;    // 0..124

  if (MODE == 0) {
    unsigned short* Sb = ep.Sout + (long)b * (H_ * (long)H_);
    const f32x4 rl4 = *(const f32x4*)&ep.rl[b * H_ + bn + c4];
#pragma unroll
    for (int it = 0; it < 16; ++it) {
      const int r = it * 8 + r8;
      const float rvr = ep.rv[b * H_ + bm + r];
      f32x4 v = *(const f32x4*)&LF[r * 128 + ((c4 + 4 * r) & 127)];
      u16x4 o;
#pragma unroll
      for (int k = 0; k < 4; ++k) o[k] = f2bf(v[k] * rvr * rl4[k]);
      *(u16x4*)&Sb[(long)(bm + r) * H_ + bn + c4] = o;
    }
  } else if (MODE == 1) {
    float* Fo = ep.Fout + (long)b * (H_ * (long)H_);
#pragma unroll
    for (int it = 0; it < 16; ++it) {
      const int r = it * 8 + r8;
      f32x4 v = *(const f32x4*)&LF[r * 128 + ((c4 + 4 * r) & 127)];
      *(f32x4*)&Fo[(long)(bm + r) * H_ + bn + c4] = v;
    }
  } else {
    const f32x4 bvv = *(const f32x4*)&biasb[bn + c4];
    // language-gate blocks fully in rows>=1024: fused row == lavg (exact)
    const bool useLavg = (!second) && (bm >= 1024);
    f32x4 lavgv = (f32x4){0.f, 0.f, 0.f, 0.f};
    if (useLavg) lavgv = *(const f32x4*)&ep.lavg[b * H_ + bn + c4];
#pragma unroll
    for (int it = 0; it < 16; ++it) {
      const int r = it * 8 + r8;
      f32x4 v = *(const f32x4*)&LF[r * 128 + ((c4 + 4 * r) & 127)];
      const long off = (long)(bm + r) * H_ + bn + c4;
      const f32x4 fv = useLavg ? lavgv : *(const f32x4*)&Fb[off];
      const u16x4 rb4 = *(const u16x4*)&RbBf[off];
      f32x4 o;
#pragma unroll
      for (int k = 0; k < 4; ++k) {
        const float x = v[k] + bvv[k];
        const float g = 1.f / (1.f + __expf(-x));
        o[k] = bf2f(rb4[k]) + fv[k] * g;
      }
      *(f32x4*)&Ob[off] = o;
    }
  }
#undef STAGE_
#undef DSRD_
#undef RDALL_P0
#undef RDALL_P1
#undef MFMA32_
}

// ---------------------------------------------------------------------------
extern "C" void kernel_launch(void* const* d_in, const int* in_sizes, int n_in,
                              void* d_out, int out_size, void* d_ws,
                              size_t ws_size, hipStream_t stream) {
  (void)in_sizes; (void)n_in; (void)out_size; (void)ws_size;
  const float* vis = (const float*)d_in[0];   // [4,1024,2048]
  const float* lang = (const float*)d_in[1];  // [4,2048,2048]
  const float* Wvl = (const float*)d_in[2];   // [2048,4096]
  const float* Wlv = (const float*)d_in[3];   // [2048,4096]

  // d_out regions: fused | vision_output | language_output
  float* out = (float*)d_out;
  float* fused = out;                      // 16,777,216 f32
  float* vis_out = out + 16777216;         //  8,388,608 f32
  float* lang_out = out + 25165824;        // 16,777,216 f32
  // scratch reuse of not-yet-final output regions:
  unsigned short* S = (unsigned short*)lang_out;     // scores/P bf16
  unsigned short* langT = (unsigned short*)vis_out;  // lang^T bf16

  // workspace layout
  char* w = (char*)d_ws;
  unsigned short* vis_bf = (unsigned short*)w;               // [4,2048,2048] bf16 (rows<1024 valid)
  unsigned short* lang_bf = (unsigned short*)(w + 33554432); // [4,2048,2048] bf16
  unsigned short* WvlHi = (unsigned short*)(w + 67108864);   // [2048,2048] bf16
  unsigned short* WlvHi = (unsigned short*)(w + 75497472);   // [2048,2048] bf16
  float* rv      = (float*)(w + 83886080);
  float* rl      = (float*)(w + 83918848);
  float* vavg    = (float*)(w + 83951616);
  float* lavg    = (float*)(w + 83984384);
  float* bias_vl = (float*)(w + 84017152);
  float* bias_lv = (float*)(w + 84049920);
  float* part    = (float*)(w + 84082688);  // 512KB partial col sums

  const long sV = 1024L * 2048, sL = 2048L * 2048, sP = 2048L * 2048;

  // vis: only the 1024 valid rows are ever read -> skip writing padded rows.
  prep_rows<<<dim3(1024, 4), 256, 0, stream>>>(vis, sV, vis_bf, sP, rv, 1024);
  prep_rows<<<dim3(2048, 4), 256, 0, stream>>>(lang, sL, lang_bf, sP, rl, 2048);
  col_sum_part_bf<<<dim3(8, 8, 8), 256, 0, stream>>>(vis_bf, lang_bf, part);
  col_sum_final<<<dim3(8, 4, 2), 256, 0, stream>>>(part, vavg, lavg);
  bias_gemv<<<512, 256, 0, stream>>>(Wvl, vavg, bias_vl);
  bias_gemv<<<512, 256, 0, stream>>>(Wlv, lavg, bias_lv);
  transpose_bf<<<dim3(32, 32, 4), 256, 0, stream>>>(lang_bf, langT);
  extract_whi<<<dim3(2048, 2), 256, 0, stream>>>(Wvl, Wlv, WvlHi, WlvHi);
  // fused rows >= 1024 are exactly lavg (uniform softmax over zero scores)
  bcast_fused<<<dim3(1024, 4), 256, 0, stream>>>(lavg, fused);

  // GEMM1: scores S[b,v<1024,l] = (vis . lang) * rv * rl  -> bf16
  EpArgs e1 = {};
  e1.Sout = S; e1.rv = rv; e1.rl = rl;
  gemm_nt<0><<<dim3(16, 8, 4), 256, 0, stream>>>(vis_bf, sP, lang_bf, sP, e1);

  softmax_rows<<<4096, 256, 0, stream>>>(S);

  // GEMM2: fused[b,v<1024,h] = P . lang  (B = lang^T, NT form) -> f32
  EpArgs e2 = {};
  e2.Fout = fused;
  gemm_nt<1><<<dim3(16, 8, 4), 256, 0, stream>>>(S, sP, langT, sP, e2);

  // GEMM3+4 merged: by<16 -> language_output, by>=16 -> vision_output
  EpArgs e34 = {};
  e34.residBf = lang_bf; e34.sResid = sP;
  e34.fusedIn = fused; e34.sFused = sP;
  e34.bias = bias_vl; e34.Oout = lang_out; e34.sOut = sL;
  e34.A2 = vis_bf; e34.B2 = WlvHi;
  e34.residBf2 = vis_bf; e34.sResid2 = sP;
  e34.bias2 = bias_lv; e34.Oout2 = vis_out; e34.sOut2 = sV;
  e34.lavg = lavg;
  gemm_nt<3><<<dim3(16, 24, 4), 256, 0, stream>>>(lang_bf, sP, WvlHi, 0L, e34);
}